// Round 1
// baseline (201.500 us; speedup 1.0000x reference)
//
#include <hip/hip_runtime.h>

#define N_CELL 100000
#define N_GENE 20000
#define DIM    128
#define N_EDGE 1000000

// ---------------------------------------------------------------------------
// Kernel 1: gene_proj[g][:] = leaky_relu(gene_z[g][:] @ W + b), slope 0.01
// Block: 256 threads, handles 16 gene rows. W (64KB) + 16 z-rows (8KB) in LDS.
// Thread t computes col = t&127 for 8 rows (t>>7)*8 .. +7.
// ---------------------------------------------------------------------------
__global__ __launch_bounds__(256) void gene_proj_kernel(
    const float* __restrict__ gene_z,
    const float* __restrict__ W,
    const float* __restrict__ b,
    float* __restrict__ out)
{
    __shared__ float Wlds[DIM * DIM];   // 64 KB
    __shared__ float zlds[16][DIM];     // 8 KB

    const int tid = threadIdx.x;

    // Cooperative load of W: 16384 floats = 4096 float4 over 256 threads.
    const float4* W4  = (const float4*)W;
    float4*       Wl4 = (float4*)Wlds;
    #pragma unroll
    for (int i = 0; i < 16; ++i) Wl4[tid + i * 256] = W4[tid + i * 256];

    // Cooperative load of 16 gene_z rows: 2048 floats = 512 float4.
    const int row0 = blockIdx.x * 16;
    const float4* Z4  = (const float4*)(gene_z + (long)row0 * DIM);
    float4*       zl4 = (float4*)&zlds[0][0];
    zl4[tid]       = Z4[tid];
    zl4[tid + 256] = Z4[tid + 256];

    __syncthreads();

    const int col   = tid & 127;
    const int rbase = (tid >> 7) * 8;   // 0 or 8

    const float bias = b[col];
    float acc[8];
    #pragma unroll
    for (int r = 0; r < 8; ++r) acc[r] = bias;

    // k-loop unrolled by 4; z read as float4 (uniform broadcast per wave).
    for (int k4 = 0; k4 < DIM / 4; ++k4) {
        float4 zv[8];
        #pragma unroll
        for (int r = 0; r < 8; ++r)
            zv[r] = ((const float4*)&zlds[rbase + r][0])[k4];
        #pragma unroll
        for (int kk = 0; kk < 4; ++kk) {
            const float w = Wlds[(k4 * 4 + kk) * DIM + col];
            #pragma unroll
            for (int r = 0; r < 8; ++r) {
                const float z = (kk == 0) ? zv[r].x : (kk == 1) ? zv[r].y
                               : (kk == 2) ? zv[r].z : zv[r].w;
                acc[r] += z * w;
            }
        }
    }

    #pragma unroll
    for (int r = 0; r < 8; ++r) {
        const float v = acc[r];
        out[(long)(row0 + rbase + r) * DIM + col] = v > 0.f ? v : 0.01f * v;
    }
}

// ---------------------------------------------------------------------------
// Kernel 2: per-edge dot + affine. 16 lanes per edge (4 edges per wave).
// Each lane loads 2 float4 from u-row and v-row (coalesced 512B segments),
// 4-step shfl_xor reduce within the 16-lane group.
// ---------------------------------------------------------------------------
__global__ __launch_bounds__(256) void edge_kernel(
    const float* __restrict__ cell_z,
    const float* __restrict__ gene_proj,
    const int*   __restrict__ src_idx,
    const int*   __restrict__ dst_idx,
    const int*   __restrict__ cell_n_id,
    const int*   __restrict__ gene_n_id,
    const float* __restrict__ cell_scale,
    const float* __restrict__ cell_bias,
    const float* __restrict__ cell_std,
    const float* __restrict__ gene_scale,
    const float* __restrict__ gene_bias,
    const float* __restrict__ gene_std,
    float* __restrict__ out)
{
    const int tid  = threadIdx.x;
    const int lane = tid & 15;                      // lane within edge-group
    const int e    = blockIdx.x * 16 + (tid >> 4);  // 16 edges per block

    const int src = src_idx[e];
    const int dst = dst_idx[e];

    const float4* u4 = (const float4*)(cell_z    + (long)src * DIM);
    const float4* v4 = (const float4*)(gene_proj + (long)dst * DIM);

    const float4 a0 = u4[lane];
    const float4 a1 = u4[lane + 16];
    const float4 b0 = v4[lane];
    const float4 b1 = v4[lane + 16];

    float dot = a0.x * b0.x + a0.y * b0.y + a0.z * b0.z + a0.w * b0.w
              + a1.x * b1.x + a1.y * b1.y + a1.z * b1.z + a1.w * b1.w;

    dot += __shfl_xor(dot, 1);
    dot += __shfl_xor(dot, 2);
    dot += __shfl_xor(dot, 4);
    dot += __shfl_xor(dot, 8);

    if (lane == 0) {
        const int sid = cell_n_id[src];
        const int did = gene_n_id[dst];
        const float loc = dot * cell_scale[sid] * gene_scale[did]
                        + cell_bias[sid] + gene_bias[did];
        const float std = cell_std[sid] * gene_std[did];
        out[e]          = loc;
        out[N_EDGE + e] = std;
    }
}

extern "C" void kernel_launch(void* const* d_in, const int* in_sizes, int n_in,
                              void* d_out, int out_size, void* d_ws, size_t ws_size,
                              hipStream_t stream) {
    const float* cell_z     = (const float*)d_in[0];
    const float* gene_z     = (const float*)d_in[1];
    const float* W_gene     = (const float*)d_in[2];
    const float* b_gene     = (const float*)d_in[3];
    const float* cell_scale = (const float*)d_in[4];
    const float* cell_bias  = (const float*)d_in[5];
    const float* cell_std   = (const float*)d_in[6];
    const float* gene_scale = (const float*)d_in[7];
    const float* gene_bias  = (const float*)d_in[8];
    const float* gene_std   = (const float*)d_in[9];
    const int*   src_idx    = (const int*)d_in[10];
    const int*   dst_idx    = (const int*)d_in[11];
    const int*   cell_n_id  = (const int*)d_in[12];
    const int*   gene_n_id  = (const int*)d_in[13];

    float* gene_proj = (float*)d_ws;   // 20000*128*4 = 10.24 MB
    float* out       = (float*)d_out;  // [2, N_EDGE] f32

    gene_proj_kernel<<<N_GENE / 16, 256, 0, stream>>>(gene_z, W_gene, b_gene, gene_proj);
    edge_kernel<<<N_EDGE / 16, 256, 0, stream>>>(
        cell_z, gene_proj, src_idx, dst_idx, cell_n_id, gene_n_id,
        cell_scale, cell_bias, cell_std, gene_scale, gene_bias, gene_std, out);
}

// Round 2
// 130.481 us; speedup vs baseline: 1.5443x; 1.5443x over previous
//
#include <hip/hip_runtime.h>

#define N_CELL 100000
#define N_GENE 20000
#define DIM    128
#define N_EDGE 1000000

// Round-to-nearest-even f32 -> bf16 (inputs are finite normals; no NaN path).
__device__ inline unsigned short f2bf(float f) {
    unsigned u = __float_as_uint(f);
    u += 0x7fffu + ((u >> 16) & 1u);
    return (unsigned short)(u >> 16);
}

// ---------------------------------------------------------------------------
// Kernel 0: cast cell_z (f32) -> bf16. 12.8M elements, 1 float4 per thread.
// ---------------------------------------------------------------------------
__global__ __launch_bounds__(256) void cast_cell_kernel(
    const float4* __restrict__ in, ushort4* __restrict__ out, int n4)
{
    const int i = blockIdx.x * 256 + threadIdx.x;
    if (i >= n4) return;
    const float4 v = in[i];
    ushort4 o;
    o.x = f2bf(v.x); o.y = f2bf(v.y); o.z = f2bf(v.z); o.w = f2bf(v.w);
    out[i] = o;
}

// ---------------------------------------------------------------------------
// Kernel 1: gene_proj[g][:] = leaky_relu(gene_z[g][:] @ W + b) -> bf16.
// 16 rows/block, 256 threads. Only z staged in LDS (8 KB -> high occupancy);
// W read from global (stride-1 across lanes, L1/L2 resident).
// ---------------------------------------------------------------------------
__global__ __launch_bounds__(256) void gene_proj_kernel(
    const float* __restrict__ gene_z,
    const float* __restrict__ W,
    const float* __restrict__ b,
    ushort* __restrict__ out)
{
    __shared__ float zlds[16][DIM];     // 8 KB

    const int tid  = threadIdx.x;
    const int row0 = blockIdx.x * 16;

    // Cooperative load of 16 gene_z rows: 2048 floats = 512 float4.
    const float4* Z4  = (const float4*)(gene_z + (long)row0 * DIM);
    float4*       zl4 = (float4*)&zlds[0][0];
    zl4[tid]       = Z4[tid];
    zl4[tid + 256] = Z4[tid + 256];
    __syncthreads();

    const int col   = tid & 127;
    const int rbase = (tid >> 7) * 8;   // 0 or 8

    const float bias = b[col];
    float acc[8];
    #pragma unroll
    for (int r = 0; r < 8; ++r) acc[r] = bias;

    for (int k4 = 0; k4 < DIM / 4; ++k4) {
        float4 zv[8];
        #pragma unroll
        for (int r = 0; r < 8; ++r)
            zv[r] = ((const float4*)&zlds[rbase + r][0])[k4];
        #pragma unroll
        for (int kk = 0; kk < 4; ++kk) {
            const float w = W[(k4 * 4 + kk) * DIM + col];   // global, cached
            #pragma unroll
            for (int r = 0; r < 8; ++r) {
                const float z = (kk == 0) ? zv[r].x : (kk == 1) ? zv[r].y
                               : (kk == 2) ? zv[r].z : zv[r].w;
                acc[r] = fmaf(z, w, acc[r]);
            }
        }
    }

    #pragma unroll
    for (int r = 0; r < 8; ++r) {
        const float v = acc[r];
        out[(long)(row0 + rbase + r) * DIM + col] = f2bf(v > 0.f ? v : 0.01f * v);
    }
}

// ---------------------------------------------------------------------------
// Kernel 2: per-edge dot + affine, bf16 gathers. 16 lanes per edge; each lane
// loads one 16B chunk (8 bf16) of the u-row and v-row -> coalesced 256B
// segments per row. 4-step shfl_xor reduce within the 16-lane group.
// ---------------------------------------------------------------------------
__global__ __launch_bounds__(256) void edge_kernel(
    const ushort* __restrict__ cell_zb,     // [N_CELL][128] bf16
    const ushort* __restrict__ gene_projb,  // [N_GENE][128] bf16
    const int*   __restrict__ src_idx,
    const int*   __restrict__ dst_idx,
    const int*   __restrict__ cell_n_id,
    const int*   __restrict__ gene_n_id,
    const float* __restrict__ cell_scale,
    const float* __restrict__ cell_bias,
    const float* __restrict__ cell_std,
    const float* __restrict__ gene_scale,
    const float* __restrict__ gene_bias,
    const float* __restrict__ gene_std,
    float* __restrict__ out)
{
    const int tid  = threadIdx.x;
    const int lane = tid & 15;
    const int e    = blockIdx.x * 16 + (tid >> 4);

    const int src = src_idx[e];
    const int dst = dst_idx[e];

    const uint4 a = ((const uint4*)(cell_zb    + (long)src * DIM))[lane];
    const uint4 v = ((const uint4*)(gene_projb + (long)dst * DIM))[lane];

    float dot = 0.f;
    #pragma unroll
    for (int c = 0; c < 4; ++c) {
        const unsigned au = (&a.x)[c];
        const unsigned vu = (&v.x)[c];
        const float alo = __uint_as_float(au << 16);
        const float ahi = __uint_as_float(au & 0xffff0000u);
        const float vlo = __uint_as_float(vu << 16);
        const float vhi = __uint_as_float(vu & 0xffff0000u);
        dot = fmaf(alo, vlo, dot);
        dot = fmaf(ahi, vhi, dot);
    }

    dot += __shfl_xor(dot, 1);
    dot += __shfl_xor(dot, 2);
    dot += __shfl_xor(dot, 4);
    dot += __shfl_xor(dot, 8);

    if (lane == 0) {
        const int sid = cell_n_id[src];
        const int did = gene_n_id[dst];
        const float loc = dot * cell_scale[sid] * gene_scale[did]
                        + cell_bias[sid] + gene_bias[did];
        const float std = cell_std[sid] * gene_std[did];
        out[e]          = loc;
        out[N_EDGE + e] = std;
    }
}

extern "C" void kernel_launch(void* const* d_in, const int* in_sizes, int n_in,
                              void* d_out, int out_size, void* d_ws, size_t ws_size,
                              hipStream_t stream) {
    const float* cell_z     = (const float*)d_in[0];
    const float* gene_z     = (const float*)d_in[1];
    const float* W_gene     = (const float*)d_in[2];
    const float* b_gene     = (const float*)d_in[3];
    const float* cell_scale = (const float*)d_in[4];
    const float* cell_bias  = (const float*)d_in[5];
    const float* cell_std   = (const float*)d_in[6];
    const float* gene_scale = (const float*)d_in[7];
    const float* gene_bias  = (const float*)d_in[8];
    const float* gene_std   = (const float*)d_in[9];
    const int*   src_idx    = (const int*)d_in[10];
    const int*   dst_idx    = (const int*)d_in[11];
    const int*   cell_n_id  = (const int*)d_in[12];
    const int*   gene_n_id  = (const int*)d_in[13];

    // Workspace layout (bf16):
    //   [0, 5.12MB)        gene_proj  20000*128*2
    //   [5.12MB, 30.72MB)  cell_z     100000*128*2
    ushort* gene_projb = (ushort*)d_ws;
    ushort* cell_zb    = (ushort*)((char*)d_ws + (size_t)N_GENE * DIM * 2);

    float* out = (float*)d_out;

    cast_cell_kernel<<<(N_CELL * DIM / 4 + 255) / 256, 256, 0, stream>>>(
        (const float4*)cell_z, (ushort4*)cell_zb, N_CELL * DIM / 4);
    gene_proj_kernel<<<N_GENE / 16, 256, 0, stream>>>(
        gene_z, W_gene, b_gene, gene_projb);
    edge_kernel<<<N_EDGE / 16, 256, 0, stream>>>(
        cell_zb, gene_projb, src_idx, dst_idx, cell_n_id, gene_n_id,
        cell_scale, cell_bias, cell_std, gene_scale, gene_bias, gene_std, out);
}

// Round 3
// 110.544 us; speedup vs baseline: 1.8228x; 1.1804x over previous
//
#include <hip/hip_runtime.h>

#define N_CELL 100000
#define N_GENE 20000
#define DIM    128
#define N_EDGE 1000000

// prep_kernel block-range partition
#define NB_PROJ 1250    // N_GENE/16
#define NB_CAST 12500   // N_CELL*DIM/4/256
#define NB_CTAB 391     // ceil(N_CELL/256)
#define NB_GTAB 79      // ceil(N_GENE/256)

// Round-to-nearest-even f32 -> bf16 (inputs finite; no NaN path needed).
__device__ inline unsigned short f2bf(float f) {
    unsigned u = __float_as_uint(f);
    u += 0x7fffu + ((u >> 16) & 1u);
    return (unsigned short)(u >> 16);
}

// ---------------------------------------------------------------------------
// Fused prep kernel. Block ranges:
//   [0, NB_PROJ)                 : gene_proj = leaky_relu(gene_z @ W + b) -> bf16
//   [NB_PROJ, +NB_CAST)          : cast cell_z f32 -> bf16
//   [.., +NB_CTAB)   (if tables) : cell_p4[c] = {scale,bias,std,0}[cell_n_id[c]]
//   [.., +NB_GTAB)   (if tables) : gene_p4[g] = {scale,bias,std,0}[gene_n_id[g]]
// All phases independent -> overlap in one dispatch.
// ---------------------------------------------------------------------------
__global__ __launch_bounds__(256) void prep_kernel(
    const float* __restrict__ gene_z,
    const float* __restrict__ W,
    const float* __restrict__ b,
    ushort* __restrict__ gene_projb,
    const float4* __restrict__ cell_z4,
    ushort4* __restrict__ cell_zb4,
    const int*   __restrict__ cell_n_id,
    const int*   __restrict__ gene_n_id,
    const float* __restrict__ cell_scale,
    const float* __restrict__ cell_bias,
    const float* __restrict__ cell_std,
    const float* __restrict__ gene_scale,
    const float* __restrict__ gene_bias,
    const float* __restrict__ gene_std,
    float4* __restrict__ cell_p4,
    float4* __restrict__ gene_p4)
{
    __shared__ float zlds[16][DIM];     // 8 KB (proj blocks only)

    const int tid = threadIdx.x;
    const int blk = blockIdx.x;

    if (blk < NB_PROJ) {
        // ---- gene projection: 16 rows per block ----
        const int row0 = blk * 16;
        const float4* Z4  = (const float4*)(gene_z + (long)row0 * DIM);
        float4*       zl4 = (float4*)&zlds[0][0];
        zl4[tid]       = Z4[tid];
        zl4[tid + 256] = Z4[tid + 256];
        __syncthreads();

        const int col   = tid & 127;
        const int rbase = (tid >> 7) * 8;   // 0 or 8

        const float bias = b[col];
        float acc[8];
        #pragma unroll
        for (int r = 0; r < 8; ++r) acc[r] = bias;

        for (int k4 = 0; k4 < DIM / 4; ++k4) {
            float4 zv[8];
            #pragma unroll
            for (int r = 0; r < 8; ++r)
                zv[r] = ((const float4*)&zlds[rbase + r][0])[k4];
            #pragma unroll
            for (int kk = 0; kk < 4; ++kk) {
                const float w = W[(k4 * 4 + kk) * DIM + col];
                #pragma unroll
                for (int r = 0; r < 8; ++r) {
                    const float z = (kk == 0) ? zv[r].x : (kk == 1) ? zv[r].y
                                   : (kk == 2) ? zv[r].z : zv[r].w;
                    acc[r] = fmaf(z, w, acc[r]);
                }
            }
        }
        #pragma unroll
        for (int r = 0; r < 8; ++r) {
            const float v = acc[r];
            gene_projb[(long)(row0 + rbase + r) * DIM + col] =
                f2bf(v > 0.f ? v : 0.01f * v);
        }
        return;
    }

    int b2 = blk - NB_PROJ;
    if (b2 < NB_CAST) {
        // ---- cell_z cast f32 -> bf16, 1 float4 per thread ----
        const int i = b2 * 256 + tid;
        const float4 v = cell_z4[i];
        ushort4 o;
        o.x = f2bf(v.x); o.y = f2bf(v.y); o.z = f2bf(v.z); o.w = f2bf(v.w);
        cell_zb4[i] = o;
        return;
    }

    b2 -= NB_CAST;
    if (b2 < NB_CTAB) {
        const int c = b2 * 256 + tid;
        if (c < N_CELL) {
            const int id = cell_n_id[c];
            cell_p4[c] = make_float4(cell_scale[id], cell_bias[id],
                                     cell_std[id], 0.f);
        }
        return;
    }

    b2 -= NB_CTAB;
    const int g = b2 * 256 + tid;
    if (g < N_GENE) {
        const int id = gene_n_id[g];
        gene_p4[g] = make_float4(gene_scale[id], gene_bias[id],
                                 gene_std[id], 0.f);
    }
}

// ---------------------------------------------------------------------------
// Edge kernel: 16 lanes per edge-group, 4 edges per group (64 edges/block).
// All 8 row-loads issued before compute -> 4x memory-level parallelism.
// After xor-reduce every lane holds all 4 dots; lanes 0-3 each finish one
// edge's scalar tail (select via cndmask chain -- no runtime reg indexing).
// ---------------------------------------------------------------------------
template<bool TAB>
__global__ __launch_bounds__(256) void edge_kernel(
    const ushort* __restrict__ cell_zb,     // [N_CELL][128] bf16
    const ushort* __restrict__ gene_projb,  // [N_GENE][128] bf16
    const int*   __restrict__ src_idx,
    const int*   __restrict__ dst_idx,
    const int*   __restrict__ cell_n_id,
    const int*   __restrict__ gene_n_id,
    const float* __restrict__ cell_scale,
    const float* __restrict__ cell_bias,
    const float* __restrict__ cell_std,
    const float* __restrict__ gene_scale,
    const float* __restrict__ gene_bias,
    const float* __restrict__ gene_std,
    const float4* __restrict__ cell_p4,
    const float4* __restrict__ gene_p4,
    float* __restrict__ out)
{
    const int tid  = threadIdx.x;
    const int lane = tid & 15;
    const int grp  = blockIdx.x * 16 + (tid >> 4);
    const int e0   = grp * 4;

    const int4 s4 = ((const int4*)src_idx)[grp];
    const int4 d4 = ((const int4*)dst_idx)[grp];

    // Issue all 8 row gathers back-to-back (compiler keeps them in flight).
    uint4 a0 = ((const uint4*)(cell_zb    + (long)s4.x * DIM))[lane];
    uint4 a1 = ((const uint4*)(cell_zb    + (long)s4.y * DIM))[lane];
    uint4 a2 = ((const uint4*)(cell_zb    + (long)s4.z * DIM))[lane];
    uint4 a3 = ((const uint4*)(cell_zb    + (long)s4.w * DIM))[lane];
    uint4 v0 = ((const uint4*)(gene_projb + (long)d4.x * DIM))[lane];
    uint4 v1 = ((const uint4*)(gene_projb + (long)d4.y * DIM))[lane];
    uint4 v2 = ((const uint4*)(gene_projb + (long)d4.z * DIM))[lane];
    uint4 v3 = ((const uint4*)(gene_projb + (long)d4.w * DIM))[lane];

    float dot0, dot1, dot2, dot3;
    #define DOT(dres, aa, vv)                                                  \
    {                                                                          \
        float d_ = 0.f;                                                        \
        _Pragma("unroll")                                                      \
        for (int c = 0; c < 4; ++c) {                                          \
            const unsigned au = (&aa.x)[c];                                    \
            const unsigned vu = (&vv.x)[c];                                    \
            d_ = fmaf(__uint_as_float(au << 16),                               \
                      __uint_as_float(vu << 16), d_);                          \
            d_ = fmaf(__uint_as_float(au & 0xffff0000u),                       \
                      __uint_as_float(vu & 0xffff0000u), d_);                  \
        }                                                                      \
        dres = d_;                                                             \
    }
    DOT(dot0, a0, v0) DOT(dot1, a1, v1) DOT(dot2, a2, v2) DOT(dot3, a3, v3)
    #undef DOT

    #define RED(d)                 \
        d += __shfl_xor(d, 1);     \
        d += __shfl_xor(d, 2);     \
        d += __shfl_xor(d, 4);     \
        d += __shfl_xor(d, 8);
    RED(dot0) RED(dot1) RED(dot2) RED(dot3)
    #undef RED

    if (lane < 4) {
        // static selects (no runtime register-array indexing)
        const float dj = (lane & 2) ? ((lane & 1) ? dot3 : dot2)
                                    : ((lane & 1) ? dot1 : dot0);
        const int sj   = (lane & 2) ? ((lane & 1) ? s4.w : s4.z)
                                    : ((lane & 1) ? s4.y : s4.x);
        const int djx  = (lane & 2) ? ((lane & 1) ? d4.w : d4.z)
                                    : ((lane & 1) ? d4.y : d4.x);
        float sc_s, b_s, sd_s, sc_d, b_d, sd_d;
        if (TAB) {
            const float4 cs = cell_p4[sj];
            const float4 gs = gene_p4[djx];
            sc_s = cs.x; b_s = cs.y; sd_s = cs.z;
            sc_d = gs.x; b_d = gs.y; sd_d = gs.z;
        } else {
            const int sid = cell_n_id[sj];
            const int did = gene_n_id[djx];
            sc_s = cell_scale[sid]; b_s = cell_bias[sid]; sd_s = cell_std[sid];
            sc_d = gene_scale[did]; b_d = gene_bias[did]; sd_d = gene_std[did];
        }
        const int e = e0 + lane;
        out[e]          = dj * sc_s * sc_d + b_s + b_d;
        out[N_EDGE + e] = sd_s * sd_d;
    }
}

extern "C" void kernel_launch(void* const* d_in, const int* in_sizes, int n_in,
                              void* d_out, int out_size, void* d_ws, size_t ws_size,
                              hipStream_t stream) {
    const float* cell_z     = (const float*)d_in[0];
    const float* gene_z     = (const float*)d_in[1];
    const float* W_gene     = (const float*)d_in[2];
    const float* b_gene     = (const float*)d_in[3];
    const float* cell_scale = (const float*)d_in[4];
    const float* cell_bias  = (const float*)d_in[5];
    const float* cell_std   = (const float*)d_in[6];
    const float* gene_scale = (const float*)d_in[7];
    const float* gene_bias  = (const float*)d_in[8];
    const float* gene_std   = (const float*)d_in[9];
    const int*   src_idx    = (const int*)d_in[10];
    const int*   dst_idx    = (const int*)d_in[11];
    const int*   cell_n_id  = (const int*)d_in[12];
    const int*   gene_n_id  = (const int*)d_in[13];

    // Workspace layout:
    //   gene_projb : N_GENE*DIM*2  = 5.12 MB
    //   cell_zb    : N_CELL*DIM*2  = 25.6 MB
    //   cell_p4    : N_CELL*16     = 1.6 MB   (if ws allows)
    //   gene_p4    : N_GENE*16     = 0.32 MB  (if ws allows)
    char* ws = (char*)d_ws;
    size_t off = 0;
    ushort* gene_projb = (ushort*)(ws + off); off += (size_t)N_GENE * DIM * 2;
    ushort* cell_zb    = (ushort*)(ws + off); off += (size_t)N_CELL * DIM * 2;
    const size_t tab_bytes = (size_t)N_CELL * 16 + (size_t)N_GENE * 16;
    const bool   tab = (ws_size >= off + tab_bytes);
    float4* cell_p4 = nullptr;
    float4* gene_p4 = nullptr;
    if (tab) {
        cell_p4 = (float4*)(ws + off); off += (size_t)N_CELL * 16;
        gene_p4 = (float4*)(ws + off); off += (size_t)N_GENE * 16;
    }

    float* out = (float*)d_out;

    const int nb_prep = NB_PROJ + NB_CAST + (tab ? (NB_CTAB + NB_GTAB) : 0);
    prep_kernel<<<nb_prep, 256, 0, stream>>>(
        gene_z, W_gene, b_gene, gene_projb,
        (const float4*)cell_z, (ushort4*)cell_zb,
        cell_n_id, gene_n_id,
        cell_scale, cell_bias, cell_std,
        gene_scale, gene_bias, gene_std,
        cell_p4, gene_p4);

    if (tab) {
        edge_kernel<true><<<N_EDGE / 64, 256, 0, stream>>>(
            cell_zb, gene_projb, src_idx, dst_idx, cell_n_id, gene_n_id,
            cell_scale, cell_bias, cell_std, gene_scale, gene_bias, gene_std,
            cell_p4, gene_p4, out);
    } else {
        edge_kernel<false><<<N_EDGE / 64, 256, 0, stream>>>(
            cell_zb, gene_projb, src_idx, dst_idx, cell_n_id, gene_n_id,
            cell_scale, cell_bias, cell_std, gene_scale, gene_bias, gene_std,
            cell_p4, gene_p4, out);
    }
}

// Round 4
// 107.882 us; speedup vs baseline: 1.8678x; 1.0247x over previous
//
#include <hip/hip_runtime.h>

#define N_CELL 100000
#define N_GENE 20000
#define DIM    128
#define N_EDGE 1000000

// prep_kernel block-range partition
#define NB_PROJ 1250    // N_GENE/16
#define NB_CAST 6250    // N_CELL*DIM/4 float4s / 512 per block
#define NB_CTAB 391     // ceil(N_CELL/256)
#define NB_GTAB 79      // ceil(N_GENE/256)

typedef float  f32x4 __attribute__((ext_vector_type(4)));

// Round-to-nearest-even f32 -> bf16 (inputs finite; no NaN path needed).
__device__ inline unsigned short f2bf(float f) {
    unsigned u = __float_as_uint(f);
    u += 0x7fffu + ((u >> 16) & 1u);
    return (unsigned short)(u >> 16);
}

// HW bf16 pair-dot: acc += a.lo*b.lo + a.hi*b.hi (f32 accumulate).
__device__ inline void dot2(float& acc, unsigned a, unsigned b) {
    asm("v_dot2_f32_bf16 %0, %1, %2, %0" : "+v"(acc) : "v"(a), "v"(b));
}

// ---------------------------------------------------------------------------
// Fused prep kernel. Block ranges:
//   [0, NB_PROJ)                 : gene_proj = leaky_relu(gene_z @ W + b) -> bf16
//   [NB_PROJ, +NB_CAST)          : cast cell_z f32 -> bf16 (2 float4/thread)
//   [.., +NB_CTAB)   (if tables) : cell_p4[c] = {scale,bias,std,0}[cell_n_id[c]]
//   [.., +NB_GTAB)   (if tables) : gene_p4[g] = {scale,bias,std,0}[gene_n_id[g]]
// ---------------------------------------------------------------------------
__global__ __launch_bounds__(256) void prep_kernel(
    const float* __restrict__ gene_z,
    const float* __restrict__ W,
    const float* __restrict__ b,
    ushort* __restrict__ gene_projb,
    const float* __restrict__ cell_z,
    ushort4* __restrict__ cell_zb4,
    const int*   __restrict__ cell_n_id,
    const int*   __restrict__ gene_n_id,
    const float* __restrict__ cell_scale,
    const float* __restrict__ cell_bias,
    const float* __restrict__ cell_std,
    const float* __restrict__ gene_scale,
    const float* __restrict__ gene_bias,
    const float* __restrict__ gene_std,
    float4* __restrict__ cell_p4,
    float4* __restrict__ gene_p4)
{
    __shared__ float zlds[16][DIM];     // 8 KB (proj blocks only)

    const int tid = threadIdx.x;
    const int blk = blockIdx.x;

    if (blk < NB_PROJ) {
        // ---- gene projection: 16 rows per block ----
        const int row0 = blk * 16;
        const f32x4* Z4  = (const f32x4*)(gene_z + (long)row0 * DIM);
        f32x4*       zl4 = (f32x4*)&zlds[0][0];
        zl4[tid]       = __builtin_nontemporal_load(Z4 + tid);
        zl4[tid + 256] = __builtin_nontemporal_load(Z4 + tid + 256);
        __syncthreads();

        const int col   = tid & 127;
        const int rbase = (tid >> 7) * 8;   // 0 or 8

        const float bias = b[col];
        float acc[8];
        #pragma unroll
        for (int r = 0; r < 8; ++r) acc[r] = bias;

        #pragma unroll 8
        for (int k4 = 0; k4 < DIM / 4; ++k4) {
            float4 zv[8];
            #pragma unroll
            for (int r = 0; r < 8; ++r)
                zv[r] = ((const float4*)&zlds[rbase + r][0])[k4];
            #pragma unroll
            for (int kk = 0; kk < 4; ++kk) {
                const float w = W[(k4 * 4 + kk) * DIM + col];
                #pragma unroll
                for (int r = 0; r < 8; ++r) {
                    const float z = (kk == 0) ? zv[r].x : (kk == 1) ? zv[r].y
                                   : (kk == 2) ? zv[r].z : zv[r].w;
                    acc[r] = fmaf(z, w, acc[r]);
                }
            }
        }
        #pragma unroll
        for (int r = 0; r < 8; ++r) {
            const float v = acc[r];
            gene_projb[(long)(row0 + rbase + r) * DIM + col] =
                f2bf(v > 0.f ? v : 0.01f * v);
        }
        return;
    }

    int b2 = blk - NB_PROJ;
    if (b2 < NB_CAST) {
        // ---- cell_z cast f32 -> bf16, 2 float4 per thread ----
        const f32x4* in4 = (const f32x4*)cell_z;
        const int base = b2 * 512 + tid;
        const f32x4 v0 = __builtin_nontemporal_load(in4 + base);
        const f32x4 v1 = __builtin_nontemporal_load(in4 + base + 256);
        ushort4 o0, o1;
        o0.x = f2bf(v0.x); o0.y = f2bf(v0.y); o0.z = f2bf(v0.z); o0.w = f2bf(v0.w);
        o1.x = f2bf(v1.x); o1.y = f2bf(v1.y); o1.z = f2bf(v1.z); o1.w = f2bf(v1.w);
        cell_zb4[base]       = o0;
        cell_zb4[base + 256] = o1;
        return;
    }

    b2 -= NB_CAST;
    if (b2 < NB_CTAB) {
        const int c = b2 * 256 + tid;
        if (c < N_CELL) {
            const int id = cell_n_id[c];
            cell_p4[c] = make_float4(cell_scale[id], cell_bias[id],
                                     cell_std[id], 0.f);
        }
        return;
    }

    b2 -= NB_CTAB;
    const int g = b2 * 256 + tid;
    if (g < N_GENE) {
        const int id = gene_n_id[g];
        gene_p4[g] = make_float4(gene_scale[id], gene_bias[id],
                                 gene_std[id], 0.f);
    }
}

// ---------------------------------------------------------------------------
// Edge kernel: 16 lanes per edge-group, 4 edges per group (64 edges/block).
// 8 row gathers issued up front (MLP); dot via v_dot2_f32_bf16 (1 inst per
// bf16-pair); 4-step shfl_xor reduce; lanes 0-3 finish one edge each.
// ---------------------------------------------------------------------------
template<bool TAB>
__global__ __launch_bounds__(256) void edge_kernel(
    const ushort* __restrict__ cell_zb,     // [N_CELL][128] bf16
    const ushort* __restrict__ gene_projb,  // [N_GENE][128] bf16
    const int*   __restrict__ src_idx,
    const int*   __restrict__ dst_idx,
    const int*   __restrict__ cell_n_id,
    const int*   __restrict__ gene_n_id,
    const float* __restrict__ cell_scale,
    const float* __restrict__ cell_bias,
    const float* __restrict__ cell_std,
    const float* __restrict__ gene_scale,
    const float* __restrict__ gene_bias,
    const float* __restrict__ gene_std,
    const float4* __restrict__ cell_p4,
    const float4* __restrict__ gene_p4,
    float* __restrict__ out)
{
    const int tid  = threadIdx.x;
    const int lane = tid & 15;
    const int grp  = blockIdx.x * 16 + (tid >> 4);
    const int e0   = grp * 4;

    const int4 s4 = ((const int4*)src_idx)[grp];
    const int4 d4 = ((const int4*)dst_idx)[grp];

    // Issue all 8 row gathers back-to-back (kept in flight by the compiler).
    uint4 a0 = ((const uint4*)(cell_zb    + (long)s4.x * DIM))[lane];
    uint4 a1 = ((const uint4*)(cell_zb    + (long)s4.y * DIM))[lane];
    uint4 a2 = ((const uint4*)(cell_zb    + (long)s4.z * DIM))[lane];
    uint4 a3 = ((const uint4*)(cell_zb    + (long)s4.w * DIM))[lane];
    uint4 v0 = ((const uint4*)(gene_projb + (long)d4.x * DIM))[lane];
    uint4 v1 = ((const uint4*)(gene_projb + (long)d4.y * DIM))[lane];
    uint4 v2 = ((const uint4*)(gene_projb + (long)d4.z * DIM))[lane];
    uint4 v3 = ((const uint4*)(gene_projb + (long)d4.w * DIM))[lane];

    float dot0 = 0.f, dot1 = 0.f, dot2v = 0.f, dot3 = 0.f;
    dot2(dot0, a0.x, v0.x); dot2(dot0, a0.y, v0.y);
    dot2(dot0, a0.z, v0.z); dot2(dot0, a0.w, v0.w);
    dot2(dot1, a1.x, v1.x); dot2(dot1, a1.y, v1.y);
    dot2(dot1, a1.z, v1.z); dot2(dot1, a1.w, v1.w);
    dot2(dot2v, a2.x, v2.x); dot2(dot2v, a2.y, v2.y);
    dot2(dot2v, a2.z, v2.z); dot2(dot2v, a2.w, v2.w);
    dot2(dot3, a3.x, v3.x); dot2(dot3, a3.y, v3.y);
    dot2(dot3, a3.z, v3.z); dot2(dot3, a3.w, v3.w);

    #define RED(d)                 \
        d += __shfl_xor(d, 1);     \
        d += __shfl_xor(d, 2);     \
        d += __shfl_xor(d, 4);     \
        d += __shfl_xor(d, 8);
    RED(dot0) RED(dot1) RED(dot2v) RED(dot3)
    #undef RED

    if (lane < 4) {
        // static selects (no runtime register-array indexing)
        const float dj = (lane & 2) ? ((lane & 1) ? dot3 : dot2v)
                                    : ((lane & 1) ? dot1 : dot0);
        const int sj   = (lane & 2) ? ((lane & 1) ? s4.w : s4.z)
                                    : ((lane & 1) ? s4.y : s4.x);
        const int djx  = (lane & 2) ? ((lane & 1) ? d4.w : d4.z)
                                    : ((lane & 1) ? d4.y : d4.x);
        float sc_s, b_s, sd_s, sc_d, b_d, sd_d;
        if (TAB) {
            const float4 cs = cell_p4[sj];
            const float4 gs = gene_p4[djx];
            sc_s = cs.x; b_s = cs.y; sd_s = cs.z;
            sc_d = gs.x; b_d = gs.y; sd_d = gs.z;
        } else {
            const int sid = cell_n_id[sj];
            const int did = gene_n_id[djx];
            sc_s = cell_scale[sid]; b_s = cell_bias[sid]; sd_s = cell_std[sid];
            sc_d = gene_scale[did]; b_d = gene_bias[did]; sd_d = gene_std[did];
        }
        const int e = e0 + lane;
        out[e]          = dj * sc_s * sc_d + b_s + b_d;
        out[N_EDGE + e] = sd_s * sd_d;
    }
}

extern "C" void kernel_launch(void* const* d_in, const int* in_sizes, int n_in,
                              void* d_out, int out_size, void* d_ws, size_t ws_size,
                              hipStream_t stream) {
    const float* cell_z     = (const float*)d_in[0];
    const float* gene_z     = (const float*)d_in[1];
    const float* W_gene     = (const float*)d_in[2];
    const float* b_gene     = (const float*)d_in[3];
    const float* cell_scale = (const float*)d_in[4];
    const float* cell_bias  = (const float*)d_in[5];
    const float* cell_std   = (const float*)d_in[6];
    const float* gene_scale = (const float*)d_in[7];
    const float* gene_bias  = (const float*)d_in[8];
    const float* gene_std   = (const float*)d_in[9];
    const int*   src_idx    = (const int*)d_in[10];
    const int*   dst_idx    = (const int*)d_in[11];
    const int*   cell_n_id  = (const int*)d_in[12];
    const int*   gene_n_id  = (const int*)d_in[13];

    // Workspace layout:
    //   gene_projb : N_GENE*DIM*2  = 5.12 MB
    //   cell_zb    : N_CELL*DIM*2  = 25.6 MB
    //   cell_p4    : N_CELL*16     = 1.6 MB   (if ws allows)
    //   gene_p4    : N_GENE*16     = 0.32 MB  (if ws allows)
    char* ws = (char*)d_ws;
    size_t off = 0;
    ushort* gene_projb = (ushort*)(ws + off); off += (size_t)N_GENE * DIM * 2;
    ushort* cell_zb    = (ushort*)(ws + off); off += (size_t)N_CELL * DIM * 2;
    const size_t tab_bytes = (size_t)N_CELL * 16 + (size_t)N_GENE * 16;
    const bool   tab = (ws_size >= off + tab_bytes);
    float4* cell_p4 = nullptr;
    float4* gene_p4 = nullptr;
    if (tab) {
        cell_p4 = (float4*)(ws + off); off += (size_t)N_CELL * 16;
        gene_p4 = (float4*)(ws + off); off += (size_t)N_GENE * 16;
    }

    float* out = (float*)d_out;

    const int nb_prep = NB_PROJ + NB_CAST + (tab ? (NB_CTAB + NB_GTAB) : 0);
    prep_kernel<<<nb_prep, 256, 0, stream>>>(
        gene_z, W_gene, b_gene, gene_projb,
        cell_z, (ushort4*)cell_zb,
        cell_n_id, gene_n_id,
        cell_scale, cell_bias, cell_std,
        gene_scale, gene_bias, gene_std,
        cell_p4, gene_p4);

    if (tab) {
        edge_kernel<true><<<N_EDGE / 64, 256, 0, stream>>>(
            cell_zb, gene_projb, src_idx, dst_idx, cell_n_id, gene_n_id,
            cell_scale, cell_bias, cell_std, gene_scale, gene_bias, gene_std,
            cell_p4, gene_p4, out);
    } else {
        edge_kernel<false><<<N_EDGE / 64, 256, 0, stream>>>(
            cell_zb, gene_projb, src_idx, dst_idx, cell_n_id, gene_n_id,
            cell_scale, cell_bias, cell_std, gene_scale, gene_bias, gene_std,
            cell_p4, gene_p4, out);
    }
}

// Round 5
// 107.056 us; speedup vs baseline: 1.8822x; 1.0077x over previous
//
#include <hip/hip_runtime.h>

#define N_CELL 100000
#define N_GENE 20000
#define DIM    128
#define N_EDGE 1000000

// --- sort geometry: 15 src-stripes x 3 dst-stripes = 45 tiles -------------
#define NS_STRIPE 15
#define NTILE     45
#define NBLK_SORT 977            // x1024 edges = 1,000,448 >= N_EDGE

// prep_kernel block-range partition (cast first: it's the BW long pole)
#define NB_CAST 6250    // N_CELL*DIM/4 float4s / 512 per block
#define NB_HIST 977
#define NB_PROJ 1250    // N_GENE/16
#define NB_CTAB 391
#define NB_GTAB 79
#define NB_PREP (NB_CAST + NB_HIST + NB_PROJ + NB_CTAB + NB_GTAB)

typedef float f32x4 __attribute__((ext_vector_type(4)));

// Round-to-nearest-even f32 -> bf16 (inputs finite; no NaN path needed).
__device__ inline unsigned short f2bf(float f) {
    unsigned u = __float_as_uint(f);
    u += 0x7fffu + ((u >> 16) & 1u);
    return (unsigned short)(u >> 16);
}

// HW bf16 pair-dot: acc += a.lo*b.lo + a.hi*b.hi (f32 accumulate).
__device__ inline void dot2(float& acc, unsigned a, unsigned b) {
    asm("v_dot2_f32_bf16 %0, %1, %2, %0" : "+v"(acc) : "v"(a), "v"(b));
}

// stripe = x / 6667  (valid for 0 <= x < 131072): floor(x*161049 / 2^30)
__device__ inline int tile_of(int s, int d) {
    const int ss = (int)(((long long)s * 161049LL) >> 30);   // 0..14
    const int ds = (int)(((long long)d * 161049LL) >> 30);   // 0..2
    return ds * NS_STRIPE + ss;
}

// ---------------------------------------------------------------------------
// Fused prep kernel. Block ranges (in launch order):
//   [0, NB_CAST)    : cast cell_z f32 -> bf16 (2 float4/thread)
//   [+NB_HIST)      : per-block tile histogram of edges (skipped if !counts)
//   [+NB_PROJ)      : gene_proj = leaky_relu(gene_z @ W + b) -> bf16
//   [+NB_CTAB)      : cell_p4[c] = {scale,bias,std,0}[cell_n_id[c]]
//   [+NB_GTAB)      : gene_p4[g] = {scale,bias,std,0}[gene_n_id[g]]
// ---------------------------------------------------------------------------
__global__ __launch_bounds__(256) void prep_kernel(
    const float* __restrict__ gene_z,
    const float* __restrict__ W,
    const float* __restrict__ b,
    ushort* __restrict__ gene_projb,
    const float* __restrict__ cell_z,
    ushort4* __restrict__ cell_zb4,
    const int*   __restrict__ src_idx,
    const int*   __restrict__ dst_idx,
    const int*   __restrict__ cell_n_id,
    const int*   __restrict__ gene_n_id,
    const float* __restrict__ cell_scale,
    const float* __restrict__ cell_bias,
    const float* __restrict__ cell_std,
    const float* __restrict__ gene_scale,
    const float* __restrict__ gene_bias,
    const float* __restrict__ gene_std,
    float4* __restrict__ cell_p4,
    float4* __restrict__ gene_p4,
    int* __restrict__ counts)       // [NTILE][NBLK_SORT], null -> skip hist
{
    __shared__ float zlds[16][DIM];     // 8 KB; hist phase aliases it as int*

    const int tid = threadIdx.x;
    int blk = blockIdx.x;

    if (blk < NB_CAST) {
        // ---- cell_z cast f32 -> bf16, 2 float4 per thread ----
        const f32x4* in4 = (const f32x4*)cell_z;
        const int base = blk * 512 + tid;
        const f32x4 v0 = __builtin_nontemporal_load(in4 + base);
        const f32x4 v1 = __builtin_nontemporal_load(in4 + base + 256);
        ushort4 o0, o1;
        o0.x = f2bf(v0.x); o0.y = f2bf(v0.y); o0.z = f2bf(v0.z); o0.w = f2bf(v0.w);
        o1.x = f2bf(v1.x); o1.y = f2bf(v1.y); o1.z = f2bf(v1.z); o1.w = f2bf(v1.w);
        cell_zb4[base]       = o0;
        cell_zb4[base + 256] = o1;
        return;
    }
    blk -= NB_CAST;

    if (blk < NB_HIST) {
        if (!counts) return;
        int* lcnt = (int*)&zlds[0][0];
        if (tid < NTILE) lcnt[tid] = 0;
        __syncthreads();
        #pragma unroll
        for (int c = 0; c < 4; ++c) {
            const int e = blk * 1024 + c * 256 + tid;
            if (e < N_EDGE) {
                const int t = tile_of(src_idx[e], dst_idx[e]);
                atomicAdd(&lcnt[t], 1);
            }
        }
        __syncthreads();
        if (tid < NTILE) counts[tid * NBLK_SORT + blk] = lcnt[tid];
        return;
    }
    blk -= NB_HIST;

    if (blk < NB_PROJ) {
        // ---- gene projection: 16 rows per block ----
        const int row0 = blk * 16;
        const f32x4* Z4  = (const f32x4*)(gene_z + (long)row0 * DIM);
        f32x4*       zl4 = (f32x4*)&zlds[0][0];
        zl4[tid]       = __builtin_nontemporal_load(Z4 + tid);
        zl4[tid + 256] = __builtin_nontemporal_load(Z4 + tid + 256);
        __syncthreads();

        const int col   = tid & 127;
        const int rbase = (tid >> 7) * 8;   // 0 or 8

        const float bias = b[col];
        float acc[8];
        #pragma unroll
        for (int r = 0; r < 8; ++r) acc[r] = bias;

        #pragma unroll 8
        for (int k4 = 0; k4 < DIM / 4; ++k4) {
            float4 zv[8];
            #pragma unroll
            for (int r = 0; r < 8; ++r)
                zv[r] = ((const float4*)&zlds[rbase + r][0])[k4];
            #pragma unroll
            for (int kk = 0; kk < 4; ++kk) {
                const float w = W[(k4 * 4 + kk) * DIM + col];
                #pragma unroll
                for (int r = 0; r < 8; ++r) {
                    const float z = (kk == 0) ? zv[r].x : (kk == 1) ? zv[r].y
                                   : (kk == 2) ? zv[r].z : zv[r].w;
                    acc[r] = fmaf(z, w, acc[r]);
                }
            }
        }
        #pragma unroll
        for (int r = 0; r < 8; ++r) {
            const float v = acc[r];
            gene_projb[(long)(row0 + rbase + r) * DIM + col] =
                f2bf(v > 0.f ? v : 0.01f * v);
        }
        return;
    }
    blk -= NB_PROJ;

    if (blk < NB_CTAB) {
        if (!cell_p4) return;
        const int c = blk * 256 + tid;
        if (c < N_CELL) {
            const int id = cell_n_id[c];
            cell_p4[c] = make_float4(cell_scale[id], cell_bias[id],
                                     cell_std[id], 0.f);
        }
        return;
    }
    blk -= NB_CTAB;

    if (!gene_p4) return;
    const int g = blk * 256 + tid;
    if (g < N_GENE) {
        const int id = gene_n_id[g];
        gene_p4[g] = make_float4(gene_scale[id], gene_bias[id],
                                 gene_std[id], 0.f);
    }
}

// ---------------------------------------------------------------------------
// scanA: per tile (blockIdx = tile), exclusive-scan its 977 per-block counts
// in place (-> per-(tile,block) offsets) and emit the tile total.
// ---------------------------------------------------------------------------
__global__ __launch_bounds__(256) void scanA_kernel(
    int* __restrict__ counts, int* __restrict__ totals)
{
    __shared__ int sd[256];
    const int t   = blockIdx.x;
    const int tid = threadIdx.x;
    int carry = 0;
    for (int c = 0; c < 4; ++c) {
        const int idx = c * 256 + tid;
        const int val = (idx < NBLK_SORT) ? counts[t * NBLK_SORT + idx] : 0;
        sd[tid] = val;
        __syncthreads();
        #pragma unroll
        for (int off = 1; off < 256; off <<= 1) {
            const int tmp = (tid >= off) ? sd[tid - off] : 0;
            __syncthreads();
            sd[tid] += tmp;
            __syncthreads();
        }
        const int incl  = sd[tid];
        const int ctot  = sd[255];
        if (idx < NBLK_SORT) counts[t * NBLK_SORT + idx] = carry + incl - val;
        carry += ctot;
        __syncthreads();
    }
    if (tid == 0) totals[t] = carry;
}

// scanB: exclusive scan of 45 tile totals -> tile bases (tiny).
__global__ void scanB_kernel(const int* __restrict__ totals,
                             int* __restrict__ bases)
{
    if (threadIdx.x == 0 && blockIdx.x == 0) {
        int s = 0;
        for (int i = 0; i < NTILE; ++i) { bases[i] = s; s += totals[i]; }
    }
}

// ---------------------------------------------------------------------------
// scatter: write (src,dst) and edge-id into tile-sorted order.
// pos = bases[tile] + offs[tile][block] + LDS-local rank.
// ---------------------------------------------------------------------------
__global__ __launch_bounds__(256) void scatter_kernel(
    const int* __restrict__ src_idx,
    const int* __restrict__ dst_idx,
    const int* __restrict__ counts,   // now per-(tile,block) offsets
    const int* __restrict__ bases,
    int2* __restrict__ sorted_sd,
    int*  __restrict__ sorted_e)
{
    __shared__ int lcnt[NTILE];
    __shared__ int lbase[NTILE];
    const int tid = threadIdx.x;
    const int blk = blockIdx.x;
    if (tid < NTILE) lcnt[tid] = 0;
    __syncthreads();

    int ts[4], rs[4], ss[4], ds[4], es[4];
    #pragma unroll
    for (int c = 0; c < 4; ++c) {
        const int e = blk * 1024 + c * 256 + tid;
        es[c] = e;
        if (e < N_EDGE) {
            ss[c] = src_idx[e];
            ds[c] = dst_idx[e];
            ts[c] = tile_of(ss[c], ds[c]);
            rs[c] = atomicAdd(&lcnt[ts[c]], 1);
        } else { ts[c] = -1; rs[c] = 0; ss[c] = 0; ds[c] = 0; }
    }
    __syncthreads();
    if (tid < NTILE) lbase[tid] = bases[tid] + counts[tid * NBLK_SORT + blk];
    __syncthreads();

    #pragma unroll
    for (int c = 0; c < 4; ++c) {
        if (ts[c] >= 0) {
            const int pos = lbase[ts[c]] + rs[c];
            sorted_sd[pos] = make_int2(ss[c], ds[c]);
            sorted_e[pos]  = es[c];
        }
    }
}

// ---------------------------------------------------------------------------
// Sorted edge kernel: 16 lanes/edge, 4 edges/group, 64 edges/block.
// Blocks XCD-chunk-swizzled so each XCD walks a contiguous sorted range
// (tile working set ~3.4MB fits the 4MB per-XCD L2).
// ---------------------------------------------------------------------------
__global__ __launch_bounds__(256) void edge_sorted_kernel(
    const ushort* __restrict__ cell_zb,
    const ushort* __restrict__ gene_projb,
    const int2* __restrict__ sorted_sd,
    const int*  __restrict__ sorted_e,
    const float4* __restrict__ cell_p4,
    const float4* __restrict__ gene_p4,
    float* __restrict__ out)
{
    // bijective XCD chunk swizzle (m204): nwg=15625, q=1953, r=1
    const int wg  = blockIdx.x;
    const int xcd = wg & 7;
    const int sub = wg >> 3;
    const int q = 15625 / 8, r = 15625 % 8;
    const int swz = ((xcd < r) ? xcd * (q + 1) : r * (q + 1) + (xcd - r) * q) + sub;

    const int tid  = threadIdx.x;
    const int lane = tid & 15;
    const int grp  = swz * 16 + (tid >> 4);

    const int4 p0 = ((const int4*)sorted_sd)[grp * 2];
    const int4 p1 = ((const int4*)sorted_sd)[grp * 2 + 1];
    const int4 e4 = ((const int4*)sorted_e)[grp];
    // p0 = {s0,d0,s1,d1}, p1 = {s2,d2,s3,d3}

    uint4 a0 = ((const uint4*)(cell_zb    + (long)p0.x * DIM))[lane];
    uint4 a1 = ((const uint4*)(cell_zb    + (long)p0.z * DIM))[lane];
    uint4 a2 = ((const uint4*)(cell_zb    + (long)p1.x * DIM))[lane];
    uint4 a3 = ((const uint4*)(cell_zb    + (long)p1.z * DIM))[lane];
    uint4 v0 = ((const uint4*)(gene_projb + (long)p0.y * DIM))[lane];
    uint4 v1 = ((const uint4*)(gene_projb + (long)p0.w * DIM))[lane];
    uint4 v2 = ((const uint4*)(gene_projb + (long)p1.y * DIM))[lane];
    uint4 v3 = ((const uint4*)(gene_projb + (long)p1.w * DIM))[lane];

    float dot0 = 0.f, dot1 = 0.f, dot2v = 0.f, dot3 = 0.f;
    dot2(dot0, a0.x, v0.x); dot2(dot0, a0.y, v0.y);
    dot2(dot0, a0.z, v0.z); dot2(dot0, a0.w, v0.w);
    dot2(dot1, a1.x, v1.x); dot2(dot1, a1.y, v1.y);
    dot2(dot1, a1.z, v1.z); dot2(dot1, a1.w, v1.w);
    dot2(dot2v, a2.x, v2.x); dot2(dot2v, a2.y, v2.y);
    dot2(dot2v, a2.z, v2.z); dot2(dot2v, a2.w, v2.w);
    dot2(dot3, a3.x, v3.x); dot2(dot3, a3.y, v3.y);
    dot2(dot3, a3.z, v3.z); dot2(dot3, a3.w, v3.w);

    #define RED(d)                 \
        d += __shfl_xor(d, 1);     \
        d += __shfl_xor(d, 2);     \
        d += __shfl_xor(d, 4);     \
        d += __shfl_xor(d, 8);
    RED(dot0) RED(dot1) RED(dot2v) RED(dot3)
    #undef RED

    if (lane < 4) {
        const float dj = (lane & 2) ? ((lane & 1) ? dot3 : dot2v)
                                    : ((lane & 1) ? dot1 : dot0);
        const int sj   = (lane & 2) ? ((lane & 1) ? p1.z : p1.x)
                                    : ((lane & 1) ? p0.z : p0.x);
        const int djx  = (lane & 2) ? ((lane & 1) ? p1.w : p1.y)
                                    : ((lane & 1) ? p0.w : p0.y);
        const int e    = (lane & 2) ? ((lane & 1) ? e4.w : e4.z)
                                    : ((lane & 1) ? e4.y : e4.x);
        const float4 cs = cell_p4[sj];
        const float4 gs = gene_p4[djx];
        out[e]          = dj * cs.x * gs.x + cs.y + gs.y;
        out[N_EDGE + e] = cs.z * gs.z;
    }
}

// ---------------------------------------------------------------------------
// Fallback unsorted edge kernel (R4) if workspace too small for sort.
// ---------------------------------------------------------------------------
template<bool TAB>
__global__ __launch_bounds__(256) void edge_kernel(
    const ushort* __restrict__ cell_zb,
    const ushort* __restrict__ gene_projb,
    const int*   __restrict__ src_idx,
    const int*   __restrict__ dst_idx,
    const int*   __restrict__ cell_n_id,
    const int*   __restrict__ gene_n_id,
    const float* __restrict__ cell_scale,
    const float* __restrict__ cell_bias,
    const float* __restrict__ cell_std,
    const float* __restrict__ gene_scale,
    const float* __restrict__ gene_bias,
    const float* __restrict__ gene_std,
    const float4* __restrict__ cell_p4,
    const float4* __restrict__ gene_p4,
    float* __restrict__ out)
{
    const int tid  = threadIdx.x;
    const int lane = tid & 15;
    const int grp  = blockIdx.x * 16 + (tid >> 4);
    const int e0   = grp * 4;

    const int4 s4 = ((const int4*)src_idx)[grp];
    const int4 d4 = ((const int4*)dst_idx)[grp];

    uint4 a0 = ((const uint4*)(cell_zb    + (long)s4.x * DIM))[lane];
    uint4 a1 = ((const uint4*)(cell_zb    + (long)s4.y * DIM))[lane];
    uint4 a2 = ((const uint4*)(cell_zb    + (long)s4.z * DIM))[lane];
    uint4 a3 = ((const uint4*)(cell_zb    + (long)s4.w * DIM))[lane];
    uint4 v0 = ((const uint4*)(gene_projb + (long)d4.x * DIM))[lane];
    uint4 v1 = ((const uint4*)(gene_projb + (long)d4.y * DIM))[lane];
    uint4 v2 = ((const uint4*)(gene_projb + (long)d4.z * DIM))[lane];
    uint4 v3 = ((const uint4*)(gene_projb + (long)d4.w * DIM))[lane];

    float dot0 = 0.f, dot1 = 0.f, dot2v = 0.f, dot3 = 0.f;
    dot2(dot0, a0.x, v0.x); dot2(dot0, a0.y, v0.y);
    dot2(dot0, a0.z, v0.z); dot2(dot0, a0.w, v0.w);
    dot2(dot1, a1.x, v1.x); dot2(dot1, a1.y, v1.y);
    dot2(dot1, a1.z, v1.z); dot2(dot1, a1.w, v1.w);
    dot2(dot2v, a2.x, v2.x); dot2(dot2v, a2.y, v2.y);
    dot2(dot2v, a2.z, v2.z); dot2(dot2v, a2.w, v2.w);
    dot2(dot3, a3.x, v3.x); dot2(dot3, a3.y, v3.y);
    dot2(dot3, a3.z, v3.z); dot2(dot3, a3.w, v3.w);

    #define RED(d)                 \
        d += __shfl_xor(d, 1);     \
        d += __shfl_xor(d, 2);     \
        d += __shfl_xor(d, 4);     \
        d += __shfl_xor(d, 8);
    RED(dot0) RED(dot1) RED(dot2v) RED(dot3)
    #undef RED

    if (lane < 4) {
        const float dj = (lane & 2) ? ((lane & 1) ? dot3 : dot2v)
                                    : ((lane & 1) ? dot1 : dot0);
        const int sj   = (lane & 2) ? ((lane & 1) ? s4.w : s4.z)
                                    : ((lane & 1) ? s4.y : s4.x);
        const int djx  = (lane & 2) ? ((lane & 1) ? d4.w : d4.z)
                                    : ((lane & 1) ? d4.y : d4.x);
        float sc_s, b_s, sd_s, sc_d, b_d, sd_d;
        if (TAB) {
            const float4 cs = cell_p4[sj];
            const float4 gs = gene_p4[djx];
            sc_s = cs.x; b_s = cs.y; sd_s = cs.z;
            sc_d = gs.x; b_d = gs.y; sd_d = gs.z;
        } else {
            const int sid = cell_n_id[sj];
            const int did = gene_n_id[djx];
            sc_s = cell_scale[sid]; b_s = cell_bias[sid]; sd_s = cell_std[sid];
            sc_d = gene_scale[did]; b_d = gene_bias[did]; sd_d = gene_std[did];
        }
        const int e = e0 + lane;
        out[e]          = dj * sc_s * sc_d + b_s + b_d;
        out[N_EDGE + e] = sd_s * sd_d;
    }
}

extern "C" void kernel_launch(void* const* d_in, const int* in_sizes, int n_in,
                              void* d_out, int out_size, void* d_ws, size_t ws_size,
                              hipStream_t stream) {
    const float* cell_z     = (const float*)d_in[0];
    const float* gene_z     = (const float*)d_in[1];
    const float* W_gene     = (const float*)d_in[2];
    const float* b_gene     = (const float*)d_in[3];
    const float* cell_scale = (const float*)d_in[4];
    const float* cell_bias  = (const float*)d_in[5];
    const float* cell_std   = (const float*)d_in[6];
    const float* gene_scale = (const float*)d_in[7];
    const float* gene_bias  = (const float*)d_in[8];
    const float* gene_std   = (const float*)d_in[9];
    const int*   src_idx    = (const int*)d_in[10];
    const int*   dst_idx    = (const int*)d_in[11];
    const int*   cell_n_id  = (const int*)d_in[12];
    const int*   gene_n_id  = (const int*)d_in[13];

    // Workspace layout:
    char* ws = (char*)d_ws;
    size_t off = 0;
    ushort* gene_projb = (ushort*)(ws + off); off += (size_t)N_GENE * DIM * 2;  // 5.12 MB
    ushort* cell_zb    = (ushort*)(ws + off); off += (size_t)N_CELL * DIM * 2;  // 25.6 MB
    const size_t base_need = off;

    // tables (1.92 MB)
    float4* cell_p4 = nullptr; float4* gene_p4 = nullptr;
    size_t off_tab = off;
    const size_t tab_need = (size_t)N_CELL * 16 + (size_t)N_GENE * 16;

    // sort structures (12.18 MB)
    int2* sorted_sd = nullptr; int* sorted_e = nullptr;
    int* counts = nullptr; int* totals = nullptr; int* bases = nullptr;

    const size_t sort_need = (size_t)N_EDGE * 8 + (size_t)N_EDGE * 4
                           + (size_t)NTILE * NBLK_SORT * 4 + 512;

    const bool tab  = (ws_size >= base_need + tab_need);
    const bool srt  = tab && (ws_size >= base_need + tab_need + sort_need);

    if (tab) {
        cell_p4 = (float4*)(ws + off_tab);
        gene_p4 = (float4*)(ws + off_tab + (size_t)N_CELL * 16);
        off = off_tab + tab_need;
    }
    if (srt) {
        sorted_sd = (int2*)(ws + off); off += (size_t)N_EDGE * 8;
        sorted_e  = (int*)(ws + off);  off += (size_t)N_EDGE * 4;
        counts    = (int*)(ws + off);  off += (size_t)NTILE * NBLK_SORT * 4;
        totals    = (int*)(ws + off);  off += 256;
        bases     = (int*)(ws + off);  off += 256;
    }

    float* out = (float*)d_out;

    prep_kernel<<<NB_PREP, 256, 0, stream>>>(
        gene_z, W_gene, b_gene, gene_projb,
        cell_z, (ushort4*)cell_zb,
        src_idx, dst_idx, cell_n_id, gene_n_id,
        cell_scale, cell_bias, cell_std,
        gene_scale, gene_bias, gene_std,
        cell_p4, gene_p4, counts);

    if (srt) {
        scanA_kernel<<<NTILE, 256, 0, stream>>>(counts, totals);
        scanB_kernel<<<1, 64, 0, stream>>>(totals, bases);
        scatter_kernel<<<NBLK_SORT, 256, 0, stream>>>(
            src_idx, dst_idx, counts, bases, sorted_sd, sorted_e);
        edge_sorted_kernel<<<N_EDGE / 64, 256, 0, stream>>>(
            cell_zb, gene_projb, sorted_sd, sorted_e, cell_p4, gene_p4, out);
    } else if (tab) {
        edge_kernel<true><<<N_EDGE / 64, 256, 0, stream>>>(
            cell_zb, gene_projb, src_idx, dst_idx, cell_n_id, gene_n_id,
            cell_scale, cell_bias, cell_std, gene_scale, gene_bias, gene_std,
            cell_p4, gene_p4, out);
    } else {
        edge_kernel<false><<<N_EDGE / 64, 256, 0, stream>>>(
            cell_zb, gene_projb, src_idx, dst_idx, cell_n_id, gene_n_id,
            cell_scale, cell_bias, cell_std, gene_scale, gene_bias, gene_std,
            nullptr, nullptr, out);
    }
}

// Round 6
// 87.162 us; speedup vs baseline: 2.3118x; 1.2282x over previous
//
#include <hip/hip_runtime.h>

#define N_CELL 100000
#define N_GENE 20000
#define DIM    128
#define N_EDGE 1000000

// --- sort geometry: 20 src-stripes x 2 dst-stripes = 40 tiles -------------
// cell stripe = 5000 rows (1.28 MB bf16), gene stripe = 10000 rows (2.56 MB)
#define NS_STRIPE 20
#define ND_STRIPE 2
#define NTILE     40
#define NBLK_SORT 977            // x1024 edges = 1,000,448 >= N_EDGE

// prep_kernel block-range partition (cast first: it's the BW long pole)
#define NB_CAST 6250    // N_CELL*DIM/4 float4s / 512 per block
#define NB_HIST 977
#define NB_PROJ 1250    // N_GENE/16
#define NB_CTAB 391
#define NB_GTAB 79
#define NB_PREP (NB_CAST + NB_HIST + NB_PROJ + NB_CTAB + NB_GTAB)

typedef float f32x4 __attribute__((ext_vector_type(4)));

// Round-to-nearest-even f32 -> bf16 (inputs finite; no NaN path needed).
__device__ inline unsigned short f2bf(float f) {
    unsigned u = __float_as_uint(f);
    u += 0x7fffu + ((u >> 16) & 1u);
    return (unsigned short)(u >> 16);
}

// HW bf16 pair-dot: acc += a.lo*b.lo + a.hi*b.hi (f32 accumulate).
__device__ inline void dot2(float& acc, unsigned a, unsigned b) {
    asm("v_dot2_f32_bf16 %0, %1, %2, %0" : "+v"(acc) : "v"(a), "v"(b));
}

// ss = s/5000 via magic mul (exact for s < 1.5M); ds = d/10000.
__device__ inline int tile_of(int s, int d) {
    const int ss = (int)(((unsigned long long)s * 429497ULL) >> 31);  // 0..19
    const int ds = (d >= 10000) ? 1 : 0;                              // 0..1
    return ds * NS_STRIPE + ss;
}

// pack (src:17b, dst:15b) into one u32. s<131072, d<32768.
__device__ inline unsigned pack_sd(int s, int d) {
    return ((unsigned)s << 15) | (unsigned)d;
}

// ---------------------------------------------------------------------------
// Fused prep kernel. Block ranges (in launch order):
//   [0, NB_CAST)  : cast cell_z f32 -> bf16 (2 float4/thread)
//   [+NB_HIST)    : per-block tile histogram of edges (skipped if !counts)
//   [+NB_PROJ)    : gene_proj = leaky_relu(gene_z @ W + b) -> bf16
//   [+NB_CTAB)    : cell_p4[c] = {scale,bias,std,0}[cell_n_id[c]]
//   [+NB_GTAB)    : gene_p4[g] = {scale,bias,std,0}[gene_n_id[g]]
// Low-VGPR proj inner loop (row pairs) so cast blocks keep 8 waves/SIMD.
// ---------------------------------------------------------------------------
__global__ __launch_bounds__(256) void prep_kernel(
    const float* __restrict__ gene_z,
    const float* __restrict__ W,
    const float* __restrict__ b,
    ushort* __restrict__ gene_projb,
    const float* __restrict__ cell_z,
    ushort4* __restrict__ cell_zb4,
    const int*   __restrict__ src_idx,
    const int*   __restrict__ dst_idx,
    const int*   __restrict__ cell_n_id,
    const int*   __restrict__ gene_n_id,
    const float* __restrict__ cell_scale,
    const float* __restrict__ cell_bias,
    const float* __restrict__ cell_std,
    const float* __restrict__ gene_scale,
    const float* __restrict__ gene_bias,
    const float* __restrict__ gene_std,
    float4* __restrict__ cell_p4,
    float4* __restrict__ gene_p4,
    int* __restrict__ counts)       // [NTILE][NBLK_SORT], null -> skip hist
{
    __shared__ float zlds[16][DIM];     // 8 KB; hist aliases it as int*

    const int tid = threadIdx.x;
    int blk = blockIdx.x;

    if (blk < NB_CAST) {
        // ---- cell_z cast f32 -> bf16, 2 float4 per thread ----
        const f32x4* in4 = (const f32x4*)cell_z;
        const int base = blk * 512 + tid;
        const f32x4 v0 = in4[base];
        const f32x4 v1 = in4[base + 256];
        ushort4 o0, o1;
        o0.x = f2bf(v0.x); o0.y = f2bf(v0.y); o0.z = f2bf(v0.z); o0.w = f2bf(v0.w);
        o1.x = f2bf(v1.x); o1.y = f2bf(v1.y); o1.z = f2bf(v1.z); o1.w = f2bf(v1.w);
        cell_zb4[base]       = o0;
        cell_zb4[base + 256] = o1;
        return;
    }
    blk -= NB_CAST;

    if (blk < NB_HIST) {
        if (!counts) return;
        int* lcnt = (int*)&zlds[0][0];
        if (tid < NTILE) lcnt[tid] = 0;
        __syncthreads();
        #pragma unroll
        for (int c = 0; c < 4; ++c) {
            const int e = blk * 1024 + c * 256 + tid;
            if (e < N_EDGE) {
                const int t = tile_of(src_idx[e], dst_idx[e]);
                atomicAdd(&lcnt[t], 1);
            }
        }
        __syncthreads();
        if (tid < NTILE) counts[tid * NBLK_SORT + blk] = lcnt[tid];
        return;
    }
    blk -= NB_HIST;

    if (blk < NB_PROJ) {
        // ---- gene projection: 16 rows per block, 8 rows per thread ----
        const int row0 = blk * 16;
        const f32x4* Z4  = (const f32x4*)(gene_z + (long)row0 * DIM);
        f32x4*       zl4 = (f32x4*)&zlds[0][0];
        zl4[tid]       = Z4[tid];
        zl4[tid + 256] = Z4[tid + 256];
        __syncthreads();

        const int col   = tid & 127;
        const int rbase = (tid >> 7) * 8;   // 0 or 8

        const float bias = b[col];
        float acc[8];
        #pragma unroll
        for (int r = 0; r < 8; ++r) acc[r] = bias;

        for (int k4 = 0; k4 < DIM / 4; ++k4) {
            const float w0 = W[(k4 * 4 + 0) * DIM + col];
            const float w1 = W[(k4 * 4 + 1) * DIM + col];
            const float w2 = W[(k4 * 4 + 2) * DIM + col];
            const float w3 = W[(k4 * 4 + 3) * DIM + col];
            #pragma unroll
            for (int rp = 0; rp < 4; ++rp) {
                const float4 za = ((const float4*)&zlds[rbase + 2*rp][0])[k4];
                const float4 zb = ((const float4*)&zlds[rbase + 2*rp + 1][0])[k4];
                acc[2*rp]     = fmaf(za.x, w0, fmaf(za.y, w1,
                                fmaf(za.z, w2, fmaf(za.w, w3, acc[2*rp]))));
                acc[2*rp + 1] = fmaf(zb.x, w0, fmaf(zb.y, w1,
                                fmaf(zb.z, w2, fmaf(zb.w, w3, acc[2*rp + 1]))));
            }
        }
        #pragma unroll
        for (int r = 0; r < 8; ++r) {
            const float v = acc[r];
            gene_projb[(long)(row0 + rbase + r) * DIM + col] =
                f2bf(v > 0.f ? v : 0.01f * v);
        }
        return;
    }
    blk -= NB_PROJ;

    if (blk < NB_CTAB) {
        if (!cell_p4) return;
        const int c = blk * 256 + tid;
        if (c < N_CELL) {
            const int id = cell_n_id[c];
            cell_p4[c] = make_float4(cell_scale[id], cell_bias[id],
                                     cell_std[id], 0.f);
        }
        return;
    }
    blk -= NB_CTAB;

    if (!gene_p4) return;
    const int g = blk * 256 + tid;
    if (g < N_GENE) {
        const int id = gene_n_id[g];
        gene_p4[g] = make_float4(gene_scale[id], gene_bias[id],
                                 gene_std[id], 0.f);
    }
}

// ---------------------------------------------------------------------------
// scanA: per tile (blockIdx = tile), exclusive-scan its 977 per-block counts
// in place (-> per-(tile,block) offsets) and emit the tile total.
// ---------------------------------------------------------------------------
__global__ __launch_bounds__(256) void scanA_kernel(
    int* __restrict__ counts, int* __restrict__ totals)
{
    __shared__ int sd[256];
    const int t   = blockIdx.x;
    const int tid = threadIdx.x;
    int carry = 0;
    for (int c = 0; c < 4; ++c) {
        const int idx = c * 256 + tid;
        const int val = (idx < NBLK_SORT) ? counts[t * NBLK_SORT + idx] : 0;
        sd[tid] = val;
        __syncthreads();
        #pragma unroll
        for (int off = 1; off < 256; off <<= 1) {
            const int tmp = (tid >= off) ? sd[tid - off] : 0;
            __syncthreads();
            sd[tid] += tmp;
            __syncthreads();
        }
        const int incl = sd[tid];
        const int ctot = sd[255];
        if (idx < NBLK_SORT) counts[t * NBLK_SORT + idx] = carry + incl - val;
        carry += ctot;
        __syncthreads();
    }
    if (tid == 0) totals[t] = carry;
}

// ---------------------------------------------------------------------------
// scatter: write packed (src,dst) to sorted position; write rank[e]
// (= sorted position) COALESCED in e-order. bases scanned in-block (40 elems).
// ---------------------------------------------------------------------------
__global__ __launch_bounds__(256) void scatter_kernel(
    const int* __restrict__ src_idx,
    const int* __restrict__ dst_idx,
    const int* __restrict__ counts,   // per-(tile,block) offsets
    const int* __restrict__ totals,
    unsigned* __restrict__ sorted_p,
    int*      __restrict__ rank)
{
    __shared__ int lcnt[NTILE];
    __shared__ int sbase[NTILE];
    __shared__ int lbase[NTILE];
    const int tid = threadIdx.x;
    const int blk = blockIdx.x;
    if (tid < NTILE) lcnt[tid] = 0;
    __syncthreads();

    int ts[4], rs[4], ss[4], ds[4];
    #pragma unroll
    for (int c = 0; c < 4; ++c) {
        const int e = blk * 1024 + c * 256 + tid;
        if (e < N_EDGE) {
            ss[c] = src_idx[e];
            ds[c] = dst_idx[e];
            ts[c] = tile_of(ss[c], ds[c]);
            rs[c] = atomicAdd(&lcnt[ts[c]], 1);
        } else { ts[c] = -1; rs[c] = 0; ss[c] = 0; ds[c] = 0; }
    }
    __syncthreads();
    if (tid == 0) {
        int s = 0;
        for (int i = 0; i < NTILE; ++i) { sbase[i] = s; s += totals[i]; }
    }
    __syncthreads();
    if (tid < NTILE) lbase[tid] = sbase[tid] + counts[tid * NBLK_SORT + blk];
    __syncthreads();

    #pragma unroll
    for (int c = 0; c < 4; ++c) {
        const int e = blk * 1024 + c * 256 + tid;
        if (ts[c] >= 0) {
            const int pos = lbase[ts[c]] + rs[c];
            sorted_p[pos] = pack_sd(ss[c], ds[c]);
            rank[e] = pos;                       // coalesced in e
        }
    }
}

// ---------------------------------------------------------------------------
// Sorted edge kernel: 16 lanes/edge, 4 edges/group, 64 edges/block.
// Reads packed u32 stream; writes res[pos]={loc,std} COALESCED (sorted order).
// XCD-chunk swizzle: each XCD walks a contiguous sorted range
// (tile working set 1.28+2.56=3.84MB fits the 4MB per-XCD L2).
// ---------------------------------------------------------------------------
__global__ __launch_bounds__(256) void edge_sorted_kernel(
    const ushort* __restrict__ cell_zb,
    const ushort* __restrict__ gene_projb,
    const unsigned* __restrict__ sorted_p,
    const float4* __restrict__ cell_p4,
    const float4* __restrict__ gene_p4,
    float2* __restrict__ res)
{
    // bijective XCD chunk swizzle (m204): nwg=15625, q=1953, r=1
    const int wg  = blockIdx.x;
    const int xcd = wg & 7;
    const int sub = wg >> 3;
    const int q = 15625 / 8, r = 15625 % 8;
    const int swz = ((xcd < r) ? xcd * (q + 1) : r * (q + 1) + (xcd - r) * q) + sub;

    const int tid  = threadIdx.x;
    const int lane = tid & 15;
    const int grp  = swz * 16 + (tid >> 4);

    const uint4 p = ((const uint4*)sorted_p)[grp];
    const int s0 = (int)(p.x >> 15), d0 = (int)(p.x & 0x7fffu);
    const int s1 = (int)(p.y >> 15), d1 = (int)(p.y & 0x7fffu);
    const int s2 = (int)(p.z >> 15), d2 = (int)(p.z & 0x7fffu);
    const int s3 = (int)(p.w >> 15), d3 = (int)(p.w & 0x7fffu);

    uint4 a0 = ((const uint4*)(cell_zb    + (long)s0 * DIM))[lane];
    uint4 a1 = ((const uint4*)(cell_zb    + (long)s1 * DIM))[lane];
    uint4 a2 = ((const uint4*)(cell_zb    + (long)s2 * DIM))[lane];
    uint4 a3 = ((const uint4*)(cell_zb    + (long)s3 * DIM))[lane];
    uint4 v0 = ((const uint4*)(gene_projb + (long)d0 * DIM))[lane];
    uint4 v1 = ((const uint4*)(gene_projb + (long)d1 * DIM))[lane];
    uint4 v2 = ((const uint4*)(gene_projb + (long)d2 * DIM))[lane];
    uint4 v3 = ((const uint4*)(gene_projb + (long)d3 * DIM))[lane];

    float dot0 = 0.f, dot1 = 0.f, dot2v = 0.f, dot3 = 0.f;
    dot2(dot0, a0.x, v0.x); dot2(dot0, a0.y, v0.y);
    dot2(dot0, a0.z, v0.z); dot2(dot0, a0.w, v0.w);
    dot2(dot1, a1.x, v1.x); dot2(dot1, a1.y, v1.y);
    dot2(dot1, a1.z, v1.z); dot2(dot1, a1.w, v1.w);
    dot2(dot2v, a2.x, v2.x); dot2(dot2v, a2.y, v2.y);
    dot2(dot2v, a2.z, v2.z); dot2(dot2v, a2.w, v2.w);
    dot2(dot3, a3.x, v3.x); dot2(dot3, a3.y, v3.y);
    dot2(dot3, a3.z, v3.z); dot2(dot3, a3.w, v3.w);

    #define RED(d)                 \
        d += __shfl_xor(d, 1);     \
        d += __shfl_xor(d, 2);     \
        d += __shfl_xor(d, 4);     \
        d += __shfl_xor(d, 8);
    RED(dot0) RED(dot1) RED(dot2v) RED(dot3)
    #undef RED

    if (lane < 4) {
        const float dj = (lane & 2) ? ((lane & 1) ? dot3 : dot2v)
                                    : ((lane & 1) ? dot1 : dot0);
        const int sj   = (lane & 2) ? ((lane & 1) ? s3 : s2)
                                    : ((lane & 1) ? s1 : s0);
        const int djx  = (lane & 2) ? ((lane & 1) ? d3 : d2)
                                    : ((lane & 1) ? d1 : d0);
        const float4 cs = cell_p4[sj];
        const float4 gs = gene_p4[djx];
        res[grp * 4 + lane] =
            make_float2(dj * cs.x * gs.x + cs.y + gs.y, cs.z * gs.z);
    }
}

// ---------------------------------------------------------------------------
// fixup: out[e] = res[rank[e]].  Coalesced rank read + out writes;
// random 8B res gathers hit the L2/L3-resident 8MB res buffer.
// 4 edges per thread.
// ---------------------------------------------------------------------------
__global__ __launch_bounds__(256) void fixup_kernel(
    const int*    __restrict__ rank,
    const float2* __restrict__ res,
    float* __restrict__ out)
{
    const int e0 = (blockIdx.x * 256 + threadIdx.x) * 4;
    if (e0 >= N_EDGE) return;
    const int4 r4 = *(const int4*)(rank + e0);
    const float2 r0 = res[r4.x];
    const float2 r1 = res[r4.y];
    const float2 r2 = res[r4.z];
    const float2 r3 = res[r4.w];
    *(float4*)(out + e0)          = make_float4(r0.x, r1.x, r2.x, r3.x);
    *(float4*)(out + N_EDGE + e0) = make_float4(r0.y, r1.y, r2.y, r3.y);
}

// ---------------------------------------------------------------------------
// Fallback unsorted edge kernel (R4) if workspace too small for sort.
// ---------------------------------------------------------------------------
template<bool TAB>
__global__ __launch_bounds__(256) void edge_kernel(
    const ushort* __restrict__ cell_zb,
    const ushort* __restrict__ gene_projb,
    const int*   __restrict__ src_idx,
    const int*   __restrict__ dst_idx,
    const int*   __restrict__ cell_n_id,
    const int*   __restrict__ gene_n_id,
    const float* __restrict__ cell_scale,
    const float* __restrict__ cell_bias,
    const float* __restrict__ cell_std,
    const float* __restrict__ gene_scale,
    const float* __restrict__ gene_bias,
    const float* __restrict__ gene_std,
    const float4* __restrict__ cell_p4,
    const float4* __restrict__ gene_p4,
    float* __restrict__ out)
{
    const int tid  = threadIdx.x;
    const int lane = tid & 15;
    const int grp  = blockIdx.x * 16 + (tid >> 4);
    const int e0   = grp * 4;

    const int4 s4 = ((const int4*)src_idx)[grp];
    const int4 d4 = ((const int4*)dst_idx)[grp];

    uint4 a0 = ((const uint4*)(cell_zb    + (long)s4.x * DIM))[lane];
    uint4 a1 = ((const uint4*)(cell_zb    + (long)s4.y * DIM))[lane];
    uint4 a2 = ((const uint4*)(cell_zb    + (long)s4.z * DIM))[lane];
    uint4 a3 = ((const uint4*)(cell_zb    + (long)s4.w * DIM))[lane];
    uint4 v0 = ((const uint4*)(gene_projb + (long)d4.x * DIM))[lane];
    uint4 v1 = ((const uint4*)(gene_projb + (long)d4.y * DIM))[lane];
    uint4 v2 = ((const uint4*)(gene_projb + (long)d4.z * DIM))[lane];
    uint4 v3 = ((const uint4*)(gene_projb + (long)d4.w * DIM))[lane];

    float dot0 = 0.f, dot1 = 0.f, dot2v = 0.f, dot3 = 0.f;
    dot2(dot0, a0.x, v0.x); dot2(dot0, a0.y, v0.y);
    dot2(dot0, a0.z, v0.z); dot2(dot0, a0.w, v0.w);
    dot2(dot1, a1.x, v1.x); dot2(dot1, a1.y, v1.y);
    dot2(dot1, a1.z, v1.z); dot2(dot1, a1.w, v1.w);
    dot2(dot2v, a2.x, v2.x); dot2(dot2v, a2.y, v2.y);
    dot2(dot2v, a2.z, v2.z); dot2(dot2v, a2.w, v2.w);
    dot2(dot3, a3.x, v3.x); dot2(dot3, a3.y, v3.y);
    dot2(dot3, a3.z, v3.z); dot2(dot3, a3.w, v3.w);

    #define RED(d)                 \
        d += __shfl_xor(d, 1);     \
        d += __shfl_xor(d, 2);     \
        d += __shfl_xor(d, 4);     \
        d += __shfl_xor(d, 8);
    RED(dot0) RED(dot1) RED(dot2v) RED(dot3)
    #undef RED

    if (lane < 4) {
        const float dj = (lane & 2) ? ((lane & 1) ? dot3 : dot2v)
                                    : ((lane & 1) ? dot1 : dot0);
        const int sj   = (lane & 2) ? ((lane & 1) ? s4.w : s4.z)
                                    : ((lane & 1) ? s4.y : s4.x);
        const int djx  = (lane & 2) ? ((lane & 1) ? d4.w : d4.z)
                                    : ((lane & 1) ? d4.y : d4.x);
        float sc_s, b_s, sd_s, sc_d, b_d, sd_d;
        if (TAB) {
            const float4 cs = cell_p4[sj];
            const float4 gs = gene_p4[djx];
            sc_s = cs.x; b_s = cs.y; sd_s = cs.z;
            sc_d = gs.x; b_d = gs.y; sd_d = gs.z;
        } else {
            const int sid = cell_n_id[sj];
            const int did = gene_n_id[djx];
            sc_s = cell_scale[sid]; b_s = cell_bias[sid]; sd_s = cell_std[sid];
            sc_d = gene_scale[did]; b_d = gene_bias[did]; sd_d = gene_std[did];
        }
        const int e = e0 + lane;
        out[e]          = dj * sc_s * sc_d + b_s + b_d;
        out[N_EDGE + e] = sd_s * sd_d;
    }
}

extern "C" void kernel_launch(void* const* d_in, const int* in_sizes, int n_in,
                              void* d_out, int out_size, void* d_ws, size_t ws_size,
                              hipStream_t stream) {
    const float* cell_z     = (const float*)d_in[0];
    const float* gene_z     = (const float*)d_in[1];
    const float* W_gene     = (const float*)d_in[2];
    const float* b_gene     = (const float*)d_in[3];
    const float* cell_scale = (const float*)d_in[4];
    const float* cell_bias  = (const float*)d_in[5];
    const float* cell_std   = (const float*)d_in[6];
    const float* gene_scale = (const float*)d_in[7];
    const float* gene_bias  = (const float*)d_in[8];
    const float* gene_std   = (const float*)d_in[9];
    const int*   src_idx    = (const int*)d_in[10];
    const int*   dst_idx    = (const int*)d_in[11];
    const int*   cell_n_id  = (const int*)d_in[12];
    const int*   gene_n_id  = (const int*)d_in[13];

    // Workspace layout:
    char* ws = (char*)d_ws;
    size_t off = 0;
    ushort* gene_projb = (ushort*)(ws + off); off += (size_t)N_GENE * DIM * 2;  // 5.12 MB
    ushort* cell_zb    = (ushort*)(ws + off); off += (size_t)N_CELL * DIM * 2;  // 25.6 MB
    const size_t base_need = off;

    // tables (1.92 MB)
    float4* cell_p4 = nullptr; float4* gene_p4 = nullptr;
    size_t off_tab = off;
    const size_t tab_need = (size_t)N_CELL * 16 + (size_t)N_GENE * 16;

    // sort structures (~16.2 MB)
    unsigned* sorted_p = nullptr; int* rank = nullptr; float2* res = nullptr;
    int* counts = nullptr; int* totals = nullptr;
    const size_t sort_need = (size_t)N_EDGE * 4      // sorted_p
                           + (size_t)N_EDGE * 4      // rank
                           + (size_t)N_EDGE * 8      // res
                           + (size_t)NTILE * NBLK_SORT * 4 + 256;

    const bool tab = (ws_size >= base_need + tab_need);
    const bool srt = tab && (ws_size >= base_need + tab_need + sort_need);

    if (tab) {
        cell_p4 = (float4*)(ws + off_tab);
        gene_p4 = (float4*)(ws + off_tab + (size_t)N_CELL * 16);
        off = off_tab + tab_need;
    }
    if (srt) {
        sorted_p = (unsigned*)(ws + off); off += (size_t)N_EDGE * 4;
        rank     = (int*)(ws + off);      off += (size_t)N_EDGE * 4;
        res      = (float2*)(ws + off);   off += (size_t)N_EDGE * 8;
        counts   = (int*)(ws + off);      off += (size_t)NTILE * NBLK_SORT * 4;
        totals   = (int*)(ws + off);      off += 256;
    }

    float* out = (float*)d_out;

    prep_kernel<<<NB_PREP, 256, 0, stream>>>(
        gene_z, W_gene, b_gene, gene_projb,
        cell_z, (ushort4*)cell_zb,
        src_idx, dst_idx, cell_n_id, gene_n_id,
        cell_scale, cell_bias, cell_std,
        gene_scale, gene_bias, gene_std,
        cell_p4, gene_p4, counts);

    if (srt) {
        scanA_kernel<<<NTILE, 256, 0, stream>>>(counts, totals);
        scatter_kernel<<<NBLK_SORT, 256, 0, stream>>>(
            src_idx, dst_idx, counts, totals, sorted_p, rank);
        edge_sorted_kernel<<<N_EDGE / 64, 256, 0, stream>>>(
            cell_zb, gene_projb, sorted_p, cell_p4, gene_p4, res);
        fixup_kernel<<<(N_EDGE / 4 + 255) / 256, 256, 0, stream>>>(rank, res, out);
    } else if (tab) {
        edge_kernel<true><<<N_EDGE / 64, 256, 0, stream>>>(
            cell_zb, gene_projb, src_idx, dst_idx, cell_n_id, gene_n_id,
            cell_scale, cell_bias, cell_std, gene_scale, gene_bias, gene_std,
            cell_p4, gene_p4, out);
    } else {
        edge_kernel<false><<<N_EDGE / 64, 256, 0, stream>>>(
            cell_zb, gene_projb, src_idx, dst_idx, cell_n_id, gene_n_id,
            cell_scale, cell_bias, cell_std, gene_scale, gene_bias, gene_std,
            nullptr, nullptr, out);
    }
}